// Round 1
// baseline (362.839 us; speedup 1.0000x reference)
//
#include <hip/hip_runtime.h>
#include <math.h>

namespace {
constexpr int kB = 8, kC = 64, kD = 32, kH = 64, kW = 64;
constexpr int kHW      = kH * kW;        // 4096
constexpr int kDHW     = kD * kHW;       // 131072
constexpr int kSpatial = kB * kDHW;      // 1048576
constexpr int kCs4     = kDHW / 4;       // channel stride in float4 units
}

// Kernel 1: per-spatial-position mean and max over the 64 channels.
// One thread = 4 consecutive w positions (float4). Lane i of a wave reads
// 16 contiguous bytes; the wave reads 1 KiB contiguous per channel step.
// Output: interleaved (avg, max) float2 pairs so the conv kernel fetches
// both channels of a tap with a single 8-byte load.
__global__ __launch_bounds__(256) void reduce_mean_max(
        const float* __restrict__ x,
        float* __restrict__ pm) {           // [kSpatial][2] interleaved
    int tid = blockIdx.x * blockDim.x + threadIdx.x;   // [0, kSpatial/4)
    int s   = tid * 4;                                  // flat spatial index
    int b   = s >> 17;                                  // s / kDHW (2^17)
    int rem = s & (kDHW - 1);
    const float4* xp = (const float4*)(x + (size_t)b * (size_t)kC * kDHW + rem);

    float4 sum = make_float4(0.f, 0.f, 0.f, 0.f);
    float4 m   = make_float4(-INFINITY, -INFINITY, -INFINITY, -INFINITY);
    #pragma unroll 8
    for (int c = 0; c < kC; ++c) {
        float4 t = xp[(size_t)c * kCs4];
        sum.x += t.x; sum.y += t.y; sum.z += t.z; sum.w += t.w;
        m.x = fmaxf(m.x, t.x); m.y = fmaxf(m.y, t.y);
        m.z = fmaxf(m.z, t.z); m.w = fmaxf(m.w, t.w);
    }
    const float inv = 1.0f / (float)kC;
    // interleave: pm[2*s+0]=avg, pm[2*s+1]=max  -> two contiguous float4s
    float4 o0 = make_float4(sum.x * inv, m.x, sum.y * inv, m.y);
    float4 o1 = make_float4(sum.z * inv, m.z, sum.w * inv, m.w);
    float4* op = (float4*)pm;
    op[tid * 2 + 0] = o0;
    op[tid * 2 + 1] = o1;
}

// Kernel 2: 3x3x3 cross-correlation over the interleaved (avg,max) map,
// SAME zero pad, fused sigmoid. 4 outputs per thread (float4 store); the
// 6-wide w-window per (kd,kh) row is loaded once and reused across taps.
// Weights layout W[0][i][kd][kh][kw]: i=0 -> avg, i=1 -> max.
__global__ __launch_bounds__(256) void conv_sigmoid(
        const float* __restrict__ pm,
        const float* __restrict__ wts,
        float* __restrict__ out) {
    __shared__ float w[54];
    if (threadIdx.x < 54) w[threadIdx.x] = wts[threadIdx.x];
    __syncthreads();

    int tid = blockIdx.x * blockDim.x + threadIdx.x;   // [0, kSpatial/4)
    int s  = tid * 4;
    int w0 = s & (kW - 1);           // 0,4,...,60
    int h  = (s >> 6) & (kH - 1);
    int bd = s >> 12;                // s / kHW
    int d  = bd & (kD - 1);
    int b  = bd >> 5;

    const float2* pmv = (const float2*)pm;

    float acc0 = 0.f, acc1 = 0.f, acc2 = 0.f, acc3 = 0.f;
    #pragma unroll
    for (int kd = 0; kd < 3; ++kd) {
        int dd = d + kd - 1;
        if ((unsigned)dd >= (unsigned)kD) continue;
        #pragma unroll
        for (int kh = 0; kh < 3; ++kh) {
            int hh = h + kh - 1;
            if ((unsigned)hh >= (unsigned)kH) continue;
            const float2* row = pmv + ((size_t)b * kDHW + (size_t)dd * kHW
                                       + (size_t)hh * kW);
            // window of 6 (avg,max) pairs covering w0-1 .. w0+4
            float2 v[6];
            #pragma unroll
            for (int j = 0; j < 6; ++j) {
                int ww = w0 - 1 + j;
                v[j] = ((unsigned)ww < (unsigned)kW) ? row[ww]
                                                     : make_float2(0.f, 0.f);
            }
            int wbase = (kd * 3 + kh) * 3;
            #pragma unroll
            for (int kw = 0; kw < 3; ++kw) {
                float wa = w[wbase + kw];
                float wm = w[27 + wbase + kw];
                acc0 = fmaf(v[kw + 0].x, wa, acc0);
                acc0 = fmaf(v[kw + 0].y, wm, acc0);
                acc1 = fmaf(v[kw + 1].x, wa, acc1);
                acc1 = fmaf(v[kw + 1].y, wm, acc1);
                acc2 = fmaf(v[kw + 2].x, wa, acc2);
                acc2 = fmaf(v[kw + 2].y, wm, acc2);
                acc3 = fmaf(v[kw + 3].x, wa, acc3);
                acc3 = fmaf(v[kw + 3].y, wm, acc3);
            }
        }
    }
    float4 o;
    o.x = __builtin_amdgcn_rcpf(1.0f + __expf(-acc0));
    o.y = __builtin_amdgcn_rcpf(1.0f + __expf(-acc1));
    o.z = __builtin_amdgcn_rcpf(1.0f + __expf(-acc2));
    o.w = __builtin_amdgcn_rcpf(1.0f + __expf(-acc3));
    ((float4*)out)[tid] = o;
}

extern "C" void kernel_launch(void* const* d_in, const int* in_sizes, int n_in,
                              void* d_out, int out_size, void* d_ws, size_t ws_size,
                              hipStream_t stream) {
    const float* x   = (const float*)d_in[0];
    const float* wts = (const float*)d_in[1];
    float* out = (float*)d_out;

    float* pm = (float*)d_ws;     // 2*kSpatial floats (8 MiB), interleaved

    {
        int threads = 256;
        int blocks  = (kSpatial / 4) / threads;   // 1024
        reduce_mean_max<<<blocks, threads, 0, stream>>>(x, pm);
    }
    {
        int threads = 256;
        int blocks  = (kSpatial / 4) / threads;   // 1024
        conv_sigmoid<<<blocks, threads, 0, stream>>>(pm, wts, out);
    }
}